// Round 11
// baseline (432.877 us; speedup 1.0000x reference)
//
#include <hip/hip_runtime.h>
#include <hip/hip_bf16.h>
#include <hip/hip_fp16.h>
#include <cstdint>
#include <cstddef>

#define NVOX 300000
#define KNBR 27
#define COUT 32
#define CINP 32                         /* padded CIN */
#define NT   (NVOX / 16)                /* 18750 tiles, exact */
#define NTP  18752                      /* padded to 4-tile chunks */
#define NCHUNK (NTP / 4)                /* 4688 64-voxel chunks */
#define RBB  1172                       /* rulebook blocks (256 voxels each) */
#define WFIXE (5 * KNBR * CINP * COUT)  /* 138240 fix weights (fp32) */
#define WFB  ((WFIXE + 255) / 256)      /* 540 */
#define WDE  (5 * COUT * CINP)          /* 5120 dense W^T (fp16) */
#define WDB  ((WDE + 255) / 256)        /* 20 */
#define ND   1172                       /* dense blocks per layer (4688 waves) */
#define FB   600                        /* fix blocks per layer (2400 waves) */

typedef __hip_bfloat16 bf16;
typedef _Float16 half8 __attribute__((ext_vector_type(8)));
typedef float floatx4 __attribute__((ext_vector_type(4)));
typedef unsigned short ushort8v __attribute__((ext_vector_type(8)));

__device__ __forceinline__ float bf2f(unsigned short u) {
    union { unsigned int i; float f; } x; x.i = ((unsigned int)u) << 16; return x.f;
}
__device__ __forceinline__ int detect_fp32(const void* b0) {
    // bn_in gamma is uniform[0.5,1.5]: bf16 even ushorts decode into [0.25,4];
    // fp32 even ushorts are mantissa bits (random).
    const unsigned short* p = (const unsigned short*)b0;
    int hits = 0;
    for (int i = 0; i < 16; i++) {
        float v = bf2f(p[2 * i]);
        if (v >= 0.25f && v <= 4.0f) hits++;
    }
    return (hits >= 8) ? 0 : 1;  // 0 = bf16, 1 = fp32
}
__device__ __forceinline__ float rdw(const void* w, int rel, int fp32) {
    return fp32 ? ((const float*)w)[rel] : __bfloat162float(((const bf16*)w)[rel]);
}

// ---- setup:
//  [0,RBB): rulebook. Wave = 64 voxels: 27 coalesced loads -> LDS -> per-lane
//           scan -> ballot -> tmask u16 per 16-voxel tile. No atomics.
//  [RBB,+WFB): fix weights fp32 [L][27][32][32] (cin zero-padded)
//  [+WDB): dense W^T fp16 [L][n=32][k=32] (cin zero-padded)
//  last: BN fold + flag ----
__global__ __launch_bounds__(256)
void setup_kernel(const int* __restrict__ nbr,
                  const void* w0, const void* w1, const void* w2, const void* w3, const void* w4,
                  const void* b0, const void* b1, const void* b2, const void* b3, const void* b4,
                  float* __restrict__ wfix, __half* __restrict__ wtf,
                  float* __restrict__ bnab, unsigned short* __restrict__ tmask,
                  int* __restrict__ flag) {
    const int tid = threadIdx.x;

    if (blockIdx.x < RBB) {
        __shared__ int snbr[4][64 * KNBR];
        int wv   = tid >> 6;
        int lane = tid & 63;
        int v0   = blockIdx.x * 256 + wv * 64;
        int base = v0 * KNBR;
#pragma unroll
        for (int i = 0; i < KNBR; i++) {
            int a = base + i * 64 + lane;
            snbr[wv][i * 64 + lane] = (a < NVOX * KNBR) ? nbr[a] : -1;
        }
        __syncthreads();
        bool f = false;
        if (v0 + lane < NVOX) {
            const int* row = &snbr[wv][lane * KNBR];
#pragma unroll
            for (int k = 0; k < KNBR; k++)
                if (k != 13) f |= (row[k] >= 0);
        }
        unsigned long long bm = __ballot(f);
        if ((lane & 15) == 0)
            tmask[(v0 >> 4) + (lane >> 4)] = (unsigned short)((bm >> (lane & 48)) & 0xFFFFULL);
        return;
    }

    const int fp32 = detect_fp32(b0);

    if (blockIdx.x < RBB + WFB) {
        int i = (blockIdx.x - RBB) * 256 + tid;
        if (i >= WFIXE) return;
        int L   = i / (KNBR * CINP * COUT);
        int rem = i % (KNBR * CINP * COUT);
        int k   = rem / (CINP * COUT);
        int kk  = (rem / COUT) % CINP;
        int nn  = rem % COUT;
        const void* w = (L == 0) ? w0 : (L == 1) ? w1 : (L == 2) ? w2 : (L == 3) ? w3 : w4;
        int cinL = (L == 0) ? 16 : 32;
        wfix[i] = (kk < cinL) ? rdw(w, (k * cinL + kk) * COUT + nn, fp32) : 0.f;
        return;
    }

    if (blockIdx.x < RBB + WFB + WDB) {
        int i = (blockIdx.x - RBB - WFB) * 256 + tid;
        if (i >= WDE) return;
        int L  = i / (COUT * CINP);
        int nn = (i / CINP) % COUT;
        int kk = i % CINP;
        const void* w = (L == 0) ? w0 : (L == 1) ? w1 : (L == 2) ? w2 : (L == 3) ? w3 : w4;
        int cinL = (L == 0) ? 16 : 32;
        float val = (kk < cinL) ? rdw(w, (13 * cinL + kk) * COUT + nn, fp32) : 0.f;
        wtf[i] = __float2half(val);
        return;
    }

    // BN fold + flag
    if (tid == 192) *flag = fp32;
    if (tid < 160) {
        int L = tid / 32, c = tid % 32;
        const void* b = (L == 0) ? b0 : (L == 1) ? b1 : (L == 2) ? b2 : (L == 3) ? b3 : b4;
        float g, be, m, v;
        if (fp32) {
            const float* q = (const float*)b;
            g = q[c]; be = q[32 + c]; m = q[64 + c]; v = q[96 + c];
        } else {
            const bf16* q = (const bf16*)b;
            g = __bfloat162float(q[c]); be = __bfloat162float(q[32 + c]);
            m = __bfloat162float(q[64 + c]); v = __bfloat162float(q[96 + c]);
        }
        float a = g * rsqrtf(v + 1e-3f);
        bnab[L * 64 + c]      = a;
        bnab[L * 64 + 32 + c] = be - a * m;
    }
}

// ---- one layer = ONE dispatch.
// Blocks [0,ND): dense MFMA. Wave = 16-voxel tile (grid-stride). A-frag = one
//   coalesced 16B load (L0: inline fp32/bf16->fp16 cvt, quads 2-3 = zero pad).
//   B-frags (W^T) in VGPRs. C layout n=lane&15, m=quad*4+reg [verified].
//   tmask[t] (wave-uniform) predicates stores: correction voxels skipped.
// Blocks [ND,ND+FB): fix. Wave grid-strides over 64-voxel tmask chunks (u64
//   load = 4 tiles), recomputes the FULL conv for flagged voxels, writes them.
// Write sets disjoint -> race-free. ----
template<bool L0, bool HAS_RES, bool FINAL>
__global__ __launch_bounds__(256)
void layer_kernel(const void* __restrict__ in,     // L0: raw feat; else fp16 AoS [v][32]
                  const int* __restrict__ nbr,
                  const unsigned short* __restrict__ tmask,
                  const float* __restrict__ wfixL, // [27][32][32] fp32
                  const __half* __restrict__ wtfL, // [32 n][32 k] fp16 W^T
                  const float* __restrict__ bnab,  // a[32], b[32]
                  const __half* __restrict__ res,  // fp16 AoS [v][32]
                  __half* __restrict__ out,        // fp16 AoS [v][32]
                  void* __restrict__ out_base,
                  const int* __restrict__ flag) {
    const int lane = threadIdx.x & 63;
    const int fp32in = (L0 || FINAL) ? *flag : 0;

    if (blockIdx.x < ND) {
        const int gw   = (blockIdx.x * 256 + threadIdx.x) >> 6;
        const int nw   = ND * 4;
        const int n    = lane & 15;
        const int quad = lane >> 4;

        const half8 bf0 = *(const half8*)((const _Float16*)wtfL + n * CINP + quad * 8);
        const half8 bf1 = *(const half8*)((const _Float16*)wtfL + (n + 16) * CINP + quad * 8);
        const float a0 = bnab[n],      bb0 = bnab[32 + n];
        const float a1 = bnab[n + 16], bb1 = bnab[48 + n];

        for (int t = gw; t < NT; t += nw) {
            int v0 = t * 16;
            half8 af;
            if (L0) {
#pragma unroll
                for (int j = 0; j < 8; j++) af[j] = (_Float16)0.f;
                if (quad < 2) {
                    if (fp32in) {
                        const float4* p = (const float4*)((const float*)in + (size_t)(v0 + n) * 16 + quad * 8);
                        float4 x0 = p[0], x1 = p[1];
                        af[0] = (_Float16)x0.x; af[1] = (_Float16)x0.y;
                        af[2] = (_Float16)x0.z; af[3] = (_Float16)x0.w;
                        af[4] = (_Float16)x1.x; af[5] = (_Float16)x1.y;
                        af[6] = (_Float16)x1.z; af[7] = (_Float16)x1.w;
                    } else {
                        ushort8v u = *(const ushort8v*)((const unsigned short*)in + (size_t)(v0 + n) * 16 + quad * 8);
#pragma unroll
                        for (int j = 0; j < 8; j++) af[j] = (_Float16)bf2f(u[j]);
                    }
                }
            } else {
                af = *(const half8*)((const _Float16*)in + ((size_t)(v0 + n) * COUT + quad * 8));
            }
            floatx4 c0 = {0.f, 0.f, 0.f, 0.f}, c1 = {0.f, 0.f, 0.f, 0.f};
            c0 = __builtin_amdgcn_mfma_f32_16x16x32_f16(af, bf0, c0, 0, 0, 0);
            c1 = __builtin_amdgcn_mfma_f32_16x16x32_f16(af, bf1, c1, 0, 0, 0);

            unsigned int m = tmask[t];
#pragma unroll
            for (int r = 0; r < 4; r++) {
                int v = v0 + quad * 4 + r;
                float y0 = fmaf(a0, c0[r], bb0);
                float y1 = fmaf(a1, c1[r], bb1);
                if (HAS_RES) {
                    y0 += __half2float(res[(size_t)v * COUT + n]);
                    y1 += __half2float(res[(size_t)v * COUT + n + 16]);
                }
                y0 = fmaxf(y0, 0.f);
                y1 = fmaxf(y1, 0.f);
                bool skip = (m >> (quad * 4 + r)) & 1;  // fix path owns this voxel

                if (FINAL) {
                    float s = y0 + y1;
#pragma unroll
                    for (int o = 1; o < 16; o <<= 1) s += __shfl_xor(s, o, 16);
                    float imp = 1.0f / (1.0f + expf(-s * (1.0f / 32.0f)));
                    if (!skip) {
                        if (fp32in) {
                            float* ox = (float*)out_base;
                            ox[(size_t)v * COUT + n]      = y0;
                            ox[(size_t)v * COUT + n + 16] = y1;
                            if (n == 0) ox[(size_t)NVOX * COUT + v] = imp;
                        } else {
                            bf16* ox = (bf16*)out_base;
                            ox[(size_t)v * COUT + n]      = __float2bfloat16(y0);
                            ox[(size_t)v * COUT + n + 16] = __float2bfloat16(y1);
                            if (n == 0) ox[(size_t)NVOX * COUT + v] = __float2bfloat16(imp);
                        }
                    }
                } else if (!skip) {
                    out[(size_t)v * COUT + n]      = __float2half(y0);
                    out[(size_t)v * COUT + n + 16] = __float2half(y1);
                }
            }
        }
        return;
    }

    // ---------- fix ----------
    int wid = ((blockIdx.x - ND) * 256 + threadIdx.x) >> 6;
    int nw  = FB * 4;
    int c   = lane & 31;
    const unsigned long long* tm64 = (const unsigned long long*)tmask;
    const __half* inh = (const __half*)in;

    for (int ch = wid; ch < NCHUNK; ch += nw) {
        unsigned long long cm = tm64[ch];
        while (cm) {
            int b = (int)__builtin_ctzll(cm);
            cm &= cm - 1;
            int v = ch * 64 + b;
            int idx = (lane < KNBR) ? nbr[(size_t)v * KNBR + lane] : -1;
            unsigned long long m = __ballot(idx >= 0) & ((1ULL << KNBR) - 1ULL);
            float acc = 0.f;
            while (m) {
                int k = (int)__builtin_ctzll(m);
                m &= m - 1;
                int src = __shfl(idx, k, 64);
                float xv = 0.f;
                if (L0) {
                    if (lane < 16)
                        xv = fp32in ? ((const float*)in)[(size_t)src * 16 + lane]
                                    : __bfloat162float(((const bf16*)in)[(size_t)src * 16 + lane]);
                } else if (lane < 32) {
                    xv = __half2float(inh[(size_t)src * COUT + lane]);
                }
                const float* wk = wfixL + (size_t)k * CINP * COUT + c;
                const int KD = L0 ? 16 : 32;
#pragma unroll 8
                for (int j = 0; j < KD; j++) {
                    float xj = __shfl(xv, j, 64);
                    acc = fmaf(xj, wk[j * COUT], acc);
                }
            }
            float y = fmaf(bnab[c], acc, bnab[32 + c]);
            if (HAS_RES) y += __half2float(res[(size_t)v * COUT + c]);
            y = fmaxf(y, 0.f);

            if (FINAL) {
                float s2 = y;
#pragma unroll
                for (int o = 16; o > 0; o >>= 1) s2 += __shfl_xor(s2, o, 32);
                float imp = 1.0f / (1.0f + expf(-s2 * (1.0f / 32.0f)));
                if (fp32in) {
                    float* ox = (float*)out_base;
                    if (lane < 32) ox[(size_t)v * COUT + c] = y;
                    if (lane == 0) ox[(size_t)NVOX * COUT + v] = imp;
                } else {
                    bf16* ox = (bf16*)out_base;
                    if (lane < 32) ox[(size_t)v * COUT + c] = __float2bfloat16(y);
                    if (lane == 0) ox[(size_t)NVOX * COUT + v] = __float2bfloat16(imp);
                }
            } else {
                if (lane < 32) out[(size_t)v * COUT + c] = __float2half(y);
            }
        }
    }
}

extern "C" void kernel_launch(void* const* d_in, const int* in_sizes, int n_in,
                              void* d_out, int out_size, void* d_ws, size_t ws_size,
                              hipStream_t stream) {
    char* ws = (char*)d_ws;
    int*            flag  = (int*)ws;
    unsigned short* tmask = (unsigned short*)(ws + 64);          // NTP u16, 8B-aligned
    float*          wfix  = (float*)(ws + ((64 + NTP * 2 + 255) & ~255));
    float*          bnab  = wfix + WFIXE;
    __half*         wtf   = (__half*)(bnab + 320);
    char*           after = (char*)(wtf + WDE);
    __half* X0 = (__half*)((((uintptr_t)after) + 255) & ~(uintptr_t)255);
    __half* X1 = X0 + (size_t)NVOX * COUT;
    __half* X2 = X1 + (size_t)NVOX * COUT;

    const void* feat = d_in[0];
    const int*  nbr  = (const int*)d_in[1];

    setup_kernel<<<dim3(RBB + WFB + WDB + 1), 256, 0, stream>>>(
        nbr, d_in[2], d_in[4], d_in[6], d_in[8], d_in[10],
        d_in[3], d_in[5], d_in[7], d_in[9], d_in[11],
        wfix, wtf, bnab, tmask, flag);

    const int WL = KNBR * CINP * COUT;
    dim3 gl(ND + FB);

    // L0: feat -> X0
    layer_kernel<true,  false, false><<<gl, 256, 0, stream>>>(feat, nbr, tmask, wfix + 0 * WL, wtf + 0 * 1024, bnab + 0 * 64, nullptr, X0, nullptr, flag);
    // L1: X0 -> X1
    layer_kernel<false, false, false><<<gl, 256, 0, stream>>>(X0,   nbr, tmask, wfix + 1 * WL, wtf + 1 * 1024, bnab + 1 * 64, nullptr, X1, nullptr, flag);
    // L2: X1 (+res X0) -> X2
    layer_kernel<false, true,  false><<<gl, 256, 0, stream>>>(X1,   nbr, tmask, wfix + 2 * WL, wtf + 2 * 1024, bnab + 2 * 64, X0, X2, nullptr, flag);
    // L3: X2 -> X0
    layer_kernel<false, false, false><<<gl, 256, 0, stream>>>(X2,   nbr, tmask, wfix + 3 * WL, wtf + 3 * 1024, bnab + 3 * 64, nullptr, X0, nullptr, flag);
    // L4: X0 (+res X2) -> d_out
    layer_kernel<false, true,  true ><<<gl, 256, 0, stream>>>(X0,   nbr, tmask, wfix + 4 * WL, wtf + 4 * 1024, bnab + 4 * 64, X2, nullptr, d_out, flag);
}